// Round 1
// baseline (85351.202 us; speedup 1.0000x reference)
//
#include <hip/hip_runtime.h>
#include <hip/hip_bf16.h>
#include <cstdint>

#define T_STEPS 8192
#define NWG 32

__device__ __forceinline__ float sigmoidf_(float v) { return 1.f / (1.f + __expf(-v)); }

// ---------- grouped linear (8 groups of 64x64) + relu, one block per row ----------
__global__ __launch_bounds__(256) void k_grouped_relu(const float* __restrict__ in,
                                                      const float* __restrict__ W,
                                                      float* __restrict__ out) {
  __shared__ float es[512];
  const int t = blockIdx.x;
  const int tid = threadIdx.x;
  const float* inr = in + (size_t)t * 512;
  ((float2*)es)[tid] = ((const float2*)inr)[tid];
  __syncthreads();
#pragma unroll
  for (int rep = 0; rep < 2; ++rep) {
    int jj = tid + rep * 256;
    int g = jj >> 6, o = jj & 63;
    const float* wp = W + (g << 12) + o;   // W[g][i][o], stride 64 over i
    const float* ep = es + (g << 6);
    float acc = 0.f;
#pragma unroll 8
    for (int i = 0; i < 64; ++i) acc = fmaf(ep[i], wp[i << 6], acc);
    out[(size_t)t * 512 + jj] = fmaxf(acc, 0.f);
  }
}

// ---------- C[M,N] = A[M,512] * B[N,512]^T + bias[N] (+ add[M,N]) ----------
__global__ __launch_bounds__(256) void k_gemm_rr(const float* __restrict__ A,
                                                 const float* __restrict__ B,
                                                 const float* __restrict__ bias,
                                                 const float* __restrict__ add,
                                                 float* __restrict__ C, int N) {
  __shared__ float As[64][68];  // [k][m]
  __shared__ float Bs[64][68];  // [k][n]
  const int bm = blockIdx.x << 6, bn = blockIdx.y << 6;
  const int tid = threadIdx.x;
  const int tx = tid & 15, ty = tid >> 4;
  float acc[4][4] = {};
  for (int k0 = 0; k0 < 512; k0 += 64) {
#pragma unroll
    for (int u = 0; u < 4; ++u) {
      int f4 = (u << 8) + tid;          // 0..1023
      int m = f4 >> 4;                  // 0..63
      int kq = (f4 & 15) << 2;          // 0..60
      float4 av = *(const float4*)(A + (size_t)(bm + m) * 512 + k0 + kq);
      As[kq + 0][m] = av.x; As[kq + 1][m] = av.y; As[kq + 2][m] = av.z; As[kq + 3][m] = av.w;
      float4 bv = *(const float4*)(B + (size_t)(bn + m) * 512 + k0 + kq);
      Bs[kq + 0][m] = bv.x; Bs[kq + 1][m] = bv.y; Bs[kq + 2][m] = bv.z; Bs[kq + 3][m] = bv.w;
    }
    __syncthreads();
#pragma unroll
    for (int k = 0; k < 64; ++k) {
      float4 a4 = *(const float4*)(&As[k][ty << 2]);
      float4 b4 = *(const float4*)(&Bs[k][tx << 2]);
      float ar[4] = {a4.x, a4.y, a4.z, a4.w};
      float br[4] = {b4.x, b4.y, b4.z, b4.w};
#pragma unroll
      for (int i = 0; i < 4; ++i)
#pragma unroll
        for (int j = 0; j < 4; ++j) acc[i][j] = fmaf(ar[i], br[j], acc[i][j]);
    }
    __syncthreads();
  }
  const int n0 = bn + (tx << 2);
  float4 bsv = *(const float4*)(bias + n0);
#pragma unroll
  for (int i = 0; i < 4; ++i) {
    int m = bm + (ty << 2) + i;
    float4 res;
    res.x = acc[i][0] + bsv.x; res.y = acc[i][1] + bsv.y;
    res.z = acc[i][2] + bsv.z; res.w = acc[i][3] + bsv.w;
    if (add) {
      float4 ad = *(const float4*)(add + (size_t)m * N + n0);
      res.x += ad.x; res.y += ad.y; res.z += ad.z; res.w += ad.w;
    }
    *(float4*)(C + (size_t)m * N + n0) = res;
  }
}

// ---------- persistent GRU scan: 32 WGs, each owns 16 hidden units ----------
__global__ __launch_bounds__(256) void k_gru_scan(const float* __restrict__ ih,
                                                  const float* __restrict__ Whh,
                                                  const float* __restrict__ bhh,
                                                  float* __restrict__ hseq,
                                                  float* __restrict__ ring,
                                                  unsigned* __restrict__ cnt) {
  __shared__ float wl[3 * 16 * 512];  // 96KB: [gate*16+jl][512]
  __shared__ float hs[512];
  const int wg = blockIdx.x, tid = threadIdx.x;
  const int jbase = wg << 4;
  for (int idx = tid; idx < 3 * 16 * 512; idx += 256) {
    int g = idx >> 13;
    int jl = (idx >> 9) & 15;
    int i = idx & 511;
    wl[idx] = Whh[((size_t)g << 18) + ((size_t)(jbase + jl) << 9) + i];
  }
  const int jl = tid >> 4, l16 = tid & 15;
  const int j = jbase + jl;
  float bh0 = 0.f, bh1 = 0.f, bh2 = 0.f;
  if (l16 == 0) { bh0 = bhh[j]; bh1 = bhh[512 + j]; bh2 = bhh[1024 + j]; }
  __syncthreads();
  const float4* w0 = (const float4*)(wl + (jl << 9) + (l16 << 5));
  const float4* w1 = (const float4*)(wl + ((16 + jl) << 9) + (l16 << 5));
  const float4* w2 = (const float4*)(wl + ((32 + jl) << 9) + (l16 << 5));
  unsigned target = 0;
  for (int t = 0; t < T_STEPS; ++t) {
    ((float2*)hs)[tid] = ((const float2*)(ring + ((t & 1) << 9)))[tid];
    __syncthreads();
    const float4* h4 = (const float4*)(hs + (l16 << 5));
    float r = 0.f, z = 0.f, n = 0.f;
#pragma unroll
    for (int q = 0; q < 8; ++q) {
      float4 hv = h4[q], a = w0[q], b = w1[q], c = w2[q];
      r = fmaf(hv.x, a.x, r); r = fmaf(hv.y, a.y, r); r = fmaf(hv.z, a.z, r); r = fmaf(hv.w, a.w, r);
      z = fmaf(hv.x, b.x, z); z = fmaf(hv.y, b.y, z); z = fmaf(hv.z, b.z, z); z = fmaf(hv.w, b.w, z);
      n = fmaf(hv.x, c.x, n); n = fmaf(hv.y, c.y, n); n = fmaf(hv.z, c.z, n); n = fmaf(hv.w, c.w, n);
    }
#pragma unroll
    for (int m = 8; m; m >>= 1) {
      r += __shfl_xor(r, m);
      z += __shfl_xor(z, m);
      n += __shfl_xor(n, m);
    }
    if (l16 == 0) {
      const float* ihp = ih + (size_t)t * 1536;
      float i0 = ihp[j], i1 = ihp[512 + j], i2 = ihp[1024 + j];
      float rr = sigmoidf_(i0 + r + bh0);
      float zz = sigmoidf_(i1 + z + bh1);
      float nn = tanhf(fmaf(rr, n + bh2, i2));
      float hnew = fmaf(zz, hs[j] - nn, nn);
      ring[(((t + 1) & 1) << 9) + j] = hnew;
      hseq[(size_t)t * 512 + j] = hnew;
    }
    __syncthreads();
    if (tid == 0) {
      __hip_atomic_fetch_add(cnt, 1u, __ATOMIC_RELEASE, __HIP_MEMORY_SCOPE_AGENT);
      target += NWG;
      while (__hip_atomic_load(cnt, __ATOMIC_ACQUIRE, __HIP_MEMORY_SCOPE_AGENT) < target)
        __builtin_amdgcn_s_sleep(1);
    }
    __syncthreads();
  }
}

// ---------- alpha = sigmoid(c . w + b), one wave per row ----------
__global__ __launch_bounds__(256) void k_alpha(const float* __restrict__ c,
                                               const float* __restrict__ w,
                                               const float* __restrict__ b,
                                               float* __restrict__ alpha) {
  const int wave = threadIdx.x >> 6, lane = threadIdx.x & 63;
  const int t = (blockIdx.x << 2) + wave;
  const float* cr = c + (size_t)t * 512;
  float acc = 0.f;
#pragma unroll
  for (int q = 0; q < 8; ++q) acc = fmaf(cr[lane + (q << 6)], w[lane + (q << 6)], acc);
#pragma unroll
  for (int m = 32; m; m >>= 1) acc += __shfl_xor(acc, m);
  if (lane == 0) alpha[t] = sigmoidf_(acc + b[0]);
}

// ---------- df_out grouped linear + tanh + conv(KT=2) add, one block per row ----------
__global__ __launch_bounds__(256) void k_dfout_conv(const float* __restrict__ c,
                                                    const float* __restrict__ Wd,
                                                    const float* __restrict__ c0,
                                                    const float* __restrict__ wc,
                                                    const float* __restrict__ bc,
                                                    float* __restrict__ out) {
  __shared__ float cs[512];
  __shared__ float A0[64 * 96];
  __shared__ float A1[64 * 96];
  __shared__ float wcs[1280];
  __shared__ float cc[960];
  const int t = blockIdx.x, tid = threadIdx.x;
  ((float2*)cs)[tid] = ((const float2*)(c + (size_t)t * 512))[tid];
  for (int idx = tid; idx < 64 * 96; idx += 256) {
    int ci = idx / 96, f = idx - ci * 96;
    size_t base = (size_t)ci * ((size_t)T_STEPS * 96) + (size_t)t * 96 + f;
    A1[idx] = c0[base];
    A0[idx] = (t == 0) ? 0.f : c0[base - 96];
  }
  for (int idx = tid; idx < 1280; idx += 256) wcs[idx] = wc[idx];
  __syncthreads();
  for (int idx = tid; idx < 960; idx += 256) {
    int f = idx / 10, co = idx - f * 10;
    float acc = bc[co];
    const float* w = wcs + (co << 7);  // (co, ci, kt)
#pragma unroll 16
    for (int ci = 0; ci < 64; ++ci) {
      acc = fmaf(A0[ci * 96 + f], w[ci * 2 + 0], acc);
      acc = fmaf(A1[ci * 96 + f], w[ci * 2 + 1], acc);
    }
    cc[idx] = acc;
  }
  __syncthreads();
  for (int idx = tid; idx < 960; idx += 256) {
    int g = idx / 120, o = idx - g * 120;
    const float* wp = Wd + g * 7680 + o;  // Wd[g][i][o], stride 120 over i
    const float* ep = cs + (g << 6);
    float acc = 0.f;
#pragma unroll 16
    for (int i = 0; i < 64; ++i) acc = fmaf(ep[i], wp[i * 120], acc);
    out[(size_t)t * 960 + idx] = tanhf(acc) + cc[idx];
  }
}

extern "C" void kernel_launch(void* const* d_in, const int* in_sizes, int n_in,
                              void* d_out, int out_size, void* d_ws, size_t ws_size,
                              hipStream_t stream) {
  const float* emb       = (const float*)d_in[0];
  const float* c0        = (const float*)d_in[1];
  const float* lin_in_w  = (const float*)d_in[2];
  const float* w_ih      = (const float*)d_in[3];  // (2,3,512,512)
  const float* w_hh      = (const float*)d_in[4];
  const float* b_ih      = (const float*)d_in[5];  // (2,3,512)
  const float* b_hh      = (const float*)d_in[6];
  const float* skip_w    = (const float*)d_in[7];
  const float* skip_b    = (const float*)d_in[8];
  const float* lin_out_w = (const float*)d_in[9];
  const float* df_skip_w = (const float*)d_in[10];
  const float* df_skip_b = (const float*)d_in[11];
  const float* fc_a_w    = (const float*)d_in[12];
  const float* fc_a_b    = (const float*)d_in[13];
  const float* df_out_w  = (const float*)d_in[14];
  const float* convp_w   = (const float*)d_in[15];
  const float* convp_b   = (const float*)d_in[16];

  const size_t T = T_STEPS;
  float* x    = (float*)d_ws;             // T*512
  float* ih   = x + T * 512;              // T*1536
  float* h0   = ih + T * 1536;            // T*512
  float* h1   = h0 + T * 512;             // T*512
  float* ring = h1 + T * 512;             // 1024 floats
  unsigned* cnt = (unsigned*)(ring + 1024);
  float* sbuf = ih;                       // reuse ih region after scans
  float* vbuf = ih + T * 512;
  float* cbuf = ih + 2 * T * 512;
  float* outc = (float*)d_out;
  float* outa = outc + T * 960;

  // x = relu(grouped_linear(emb, lin_in_w))
  k_grouped_relu<<<T_STEPS, 256, 0, stream>>>(emb, lin_in_w, x);
  // ih0 = x @ W_ih0^T + b_ih0
  k_gemm_rr<<<dim3(128, 24), 256, 0, stream>>>(x, w_ih, b_ih, nullptr, ih, 1536);
  // layer-0 scan
  hipMemsetAsync(ring, 0, 1024 * 4 + 64, stream);
  k_gru_scan<<<NWG, 256, 0, stream>>>(ih, w_hh, b_hh, h0, ring, cnt);
  // ih1 = h0 @ W_ih1^T + b_ih1
  k_gemm_rr<<<dim3(128, 24), 256, 0, stream>>>(h0, w_ih + 786432, b_ih + 1536, nullptr, ih, 1536);
  // layer-1 scan
  hipMemsetAsync(ring, 0, 1024 * 4 + 64, stream);
  k_gru_scan<<<NWG, 256, 0, stream>>>(ih, w_hh + 786432, b_hh + 1536, h1, ring, cnt);
  // s = h1 + x @ skip_w^T + skip_b
  k_gemm_rr<<<dim3(128, 8), 256, 0, stream>>>(x, skip_w, skip_b, h1, sbuf, 512);
  // v = relu(grouped_linear(s, lin_out_w))
  k_grouped_relu<<<T_STEPS, 256, 0, stream>>>(sbuf, lin_out_w, vbuf);
  // c = v + emb @ df_skip_w^T + df_skip_b
  k_gemm_rr<<<dim3(128, 8), 256, 0, stream>>>(emb, df_skip_w, df_skip_b, vbuf, cbuf, 512);
  // alpha = sigmoid(c @ fc_a_w^T + fc_a_b)
  k_alpha<<<T_STEPS / 4, 256, 0, stream>>>(cbuf, fc_a_w, fc_a_b, outa);
  // out = tanh(grouped_linear(c, df_out_w)) + conv(c0)
  k_dfout_conv<<<T_STEPS, 256, 0, stream>>>(cbuf, df_out_w, c0, convp_w, convp_b, outc);
  (void)in_sizes; (void)n_in; (void)out_size; (void)ws_size;
}

// Round 3
// 34899.475 us; speedup vs baseline: 2.4456x; 2.4456x over previous
//
#include <hip/hip_runtime.h>
#include <hip/hip_bf16.h>
#include <cstdint>

#define T_STEPS 8192
#define NWG2 64

__device__ __forceinline__ float sigmoidf_(float v) { return 1.f / (1.f + __expf(-v)); }

__device__ __forceinline__ void acc4(float& acc, const float4& wv, const float4& hv) {
  acc = fmaf(hv.x, wv.x, acc); acc = fmaf(hv.y, wv.y, acc);
  acc = fmaf(hv.z, wv.z, acc); acc = fmaf(hv.w, wv.w, acc);
}

// ---------- grouped linear (8 groups of 64x64) + relu, one block per row ----------
__global__ __launch_bounds__(256) void k_grouped_relu(const float* __restrict__ in,
                                                      const float* __restrict__ W,
                                                      float* __restrict__ out) {
  __shared__ float es[512];
  const int t = blockIdx.x;
  const int tid = threadIdx.x;
  const float* inr = in + (size_t)t * 512;
  ((float2*)es)[tid] = ((const float2*)inr)[tid];
  __syncthreads();
#pragma unroll
  for (int rep = 0; rep < 2; ++rep) {
    int jj = tid + rep * 256;
    int g = jj >> 6, o = jj & 63;
    const float* wp = W + (g << 12) + o;   // W[g][i][o], stride 64 over i
    const float* ep = es + (g << 6);
    float acc = 0.f;
#pragma unroll 8
    for (int i = 0; i < 64; ++i) acc = fmaf(ep[i], wp[i << 6], acc);
    out[(size_t)t * 512 + jj] = fmaxf(acc, 0.f);
  }
}

// ---------- C[M,N] = A[M,512] * B[N,512]^T + bias[N] (+ add[M,N]) ----------
__global__ __launch_bounds__(256) void k_gemm_rr(const float* __restrict__ A,
                                                 const float* __restrict__ B,
                                                 const float* __restrict__ bias,
                                                 const float* __restrict__ add,
                                                 float* __restrict__ C, int N) {
  __shared__ float As[64][68];  // [k][m]
  __shared__ float Bs[64][68];  // [k][n]
  const int bm = blockIdx.x << 6, bn = blockIdx.y << 6;
  const int tid = threadIdx.x;
  const int tx = tid & 15, ty = tid >> 4;
  float acc[4][4] = {};
  for (int k0 = 0; k0 < 512; k0 += 64) {
#pragma unroll
    for (int u = 0; u < 4; ++u) {
      int f4 = (u << 8) + tid;          // 0..1023
      int m = f4 >> 4;                  // 0..63
      int kq = (f4 & 15) << 2;          // 0..60
      float4 av = *(const float4*)(A + (size_t)(bm + m) * 512 + k0 + kq);
      As[kq + 0][m] = av.x; As[kq + 1][m] = av.y; As[kq + 2][m] = av.z; As[kq + 3][m] = av.w;
      float4 bv = *(const float4*)(B + (size_t)(bn + m) * 512 + k0 + kq);
      Bs[kq + 0][m] = bv.x; Bs[kq + 1][m] = bv.y; Bs[kq + 2][m] = bv.z; Bs[kq + 3][m] = bv.w;
    }
    __syncthreads();
#pragma unroll
    for (int k = 0; k < 64; ++k) {
      float4 a4 = *(const float4*)(&As[k][ty << 2]);
      float4 b4 = *(const float4*)(&Bs[k][tx << 2]);
      float ar[4] = {a4.x, a4.y, a4.z, a4.w};
      float br[4] = {b4.x, b4.y, b4.z, b4.w};
#pragma unroll
      for (int i = 0; i < 4; ++i)
#pragma unroll
        for (int j = 0; j < 4; ++j) acc[i][j] = fmaf(ar[i], br[j], acc[i][j]);
    }
    __syncthreads();
  }
  const int n0 = bn + (tx << 2);
  float4 bsv = *(const float4*)(bias + n0);
#pragma unroll
  for (int i = 0; i < 4; ++i) {
    int m = bm + (ty << 2) + i;
    float4 res;
    res.x = acc[i][0] + bsv.x; res.y = acc[i][1] + bsv.y;
    res.z = acc[i][2] + bsv.z; res.w = acc[i][3] + bsv.w;
    if (add) {
      float4 ad = *(const float4*)(add + (size_t)m * N + n0);
      res.x += ad.x; res.y += ad.y; res.z += ad.z; res.w += ad.w;
    }
    *(float4*)(C + (size_t)m * N + n0) = res;
  }
}

// ---------- fused 2-layer persistent GRU scan, software-pipelined ----------
// 64 WGs x 256 threads. WG owns rows [wg*8, wg*8+8) of BOTH layers.
// Thread (jl = tid>>5, l32 = tid&31) holds 16-float slices of W_hh0, W_ih1, W_hh1
// for its row in registers (36 float4). Tick t computes h0[t] and h1[t-1].
__global__ __launch_bounds__(256, 1) void k_gru_fused(
    const float* __restrict__ ih0,   // [T][1536] precomputed x@W_ih0^T + b_ih0
    const float* __restrict__ Whh0, const float* __restrict__ bhh0,
    const float* __restrict__ Wih1, const float* __restrict__ bih1,
    const float* __restrict__ Whh1, const float* __restrict__ bhh1,
    float* __restrict__ h1seq,       // [T][512]
    float* __restrict__ b0,          // [2][512] zeroed
    float* __restrict__ b1,          // [2][512] zeroed
    unsigned* __restrict__ flags) {  // [NWG2*32] zeroed
  const int wg = blockIdx.x, tid = threadIdx.x;
  const int l32 = tid & 31, jl = tid >> 5;   // jl 0..7
  const int r = (wg << 3) + jl;              // global row 0..511
  // load weight slices into registers: elements l32*4 + q*128 .. +3 of row r
  float4 w0r[3][4], w1i[3][4], w1h[3][4];
#pragma unroll
  for (int g = 0; g < 3; ++g)
#pragma unroll
    for (int q = 0; q < 4; ++q) {
      size_t off = ((size_t)g << 18) + ((size_t)r << 9) + (l32 << 2) + (q << 7);
      w0r[g][q] = *(const float4*)(Whh0 + off);
      w1i[g][q] = *(const float4*)(Wih1 + off);
      w1h[g][q] = *(const float4*)(Whh1 + off);
    }
  float bh00 = 0, bh01 = 0, bh02 = 0, bi10 = 0, bi11 = 0, bi12 = 0,
        bh10 = 0, bh11 = 0, bh12 = 0;
  if (l32 == 0) {
    bh00 = bhh0[r]; bh01 = bhh0[512 + r]; bh02 = bhh0[1024 + r];
    bi10 = bih1[r]; bi11 = bih1[512 + r]; bi12 = bih1[1024 + r];
    bh10 = bhh1[r]; bh11 = bhh1[512 + r]; bh12 = bhh1[1024 + r];
  }
  float h0own = 0.f, h1own = 0.f;  // valid in l32==0 lanes
  unsigned target = 1;
  for (int t = 0; t <= T_STEPS; ++t) {
    const float* r0 = b0 + (((t + 1) & 1) << 9);  // h0[t-1]
    const float* r1 = b1 + (((t + 1) & 1) << 9);  // h1[t-2]
    float* w0p = b0 + ((t & 1) << 9);
    float* w1p = b1 + ((t & 1) << 9);
    // prefetchable ih0 row (independent of barrier data)
    float i0 = 0, i1 = 0, i2 = 0;
    if (l32 == 0 && t < T_STEPS) {
      const float* ihp = ih0 + (size_t)t * 1536 + r;
      i0 = ihp[0]; i1 = ihp[512]; i2 = ihp[1024];
    }
    float4 hv0[4], hv1[4];
#pragma unroll
    for (int q = 0; q < 4; ++q) hv0[q] = *(const float4*)(r0 + (l32 << 2) + (q << 7));
#pragma unroll
    for (int q = 0; q < 4; ++q) hv1[q] = *(const float4*)(r1 + (l32 << 2) + (q << 7));
    float a0 = 0, a1 = 0, a2 = 0;   // h0[t-1] . Whh0[row]
    float e0 = 0, e1 = 0, e2 = 0;   // h0[t-1] . Wih1[row]
    float d0 = 0, d1 = 0, d2 = 0;   // h1[t-2] . Whh1[row]
#pragma unroll
    for (int q = 0; q < 4; ++q) {
      float4 h = hv0[q];
      acc4(a0, w0r[0][q], h); acc4(a1, w0r[1][q], h); acc4(a2, w0r[2][q], h);
      acc4(e0, w1i[0][q], h); acc4(e1, w1i[1][q], h); acc4(e2, w1i[2][q], h);
      float4 g = hv1[q];
      acc4(d0, w1h[0][q], g); acc4(d1, w1h[1][q], g); acc4(d2, w1h[2][q], g);
    }
#pragma unroll
    for (int m = 16; m; m >>= 1) {
      a0 += __shfl_xor(a0, m); a1 += __shfl_xor(a1, m); a2 += __shfl_xor(a2, m);
      e0 += __shfl_xor(e0, m); e1 += __shfl_xor(e1, m); e2 += __shfl_xor(e2, m);
      d0 += __shfl_xor(d0, m); d1 += __shfl_xor(d1, m); d2 += __shfl_xor(d2, m);
    }
    if (l32 == 0) {
      if (t < T_STEPS) {
        float rr = sigmoidf_(i0 + a0 + bh00);
        float zz = sigmoidf_(i1 + a1 + bh01);
        float nn = tanhf(fmaf(rr, a2 + bh02, i2));
        h0own = fmaf(zz, h0own - nn, nn);
        w0p[r] = h0own;
      }
      if (t >= 1) {
        float rr = sigmoidf_(e0 + bi10 + d0 + bh10);
        float zz = sigmoidf_(e1 + bi11 + d1 + bh11);
        float nn = tanhf(fmaf(rr, d2 + bh12, e2 + bi12));
        h1own = fmaf(zz, h1own - nn, nn);
        w1p[r] = h1own;
        h1seq[(size_t)(t - 1) * 512 + r] = h1own;
      }
    }
    if (t == T_STEPS) break;
    __syncthreads();  // drains each wave's stores before barrier
    if (tid == 0)
      __hip_atomic_store(flags + (wg << 5), target, __ATOMIC_RELEASE,
                         __HIP_MEMORY_SCOPE_AGENT);
    if (tid < NWG2) {
      while (__hip_atomic_load(flags + (tid << 5), __ATOMIC_ACQUIRE,
                               __HIP_MEMORY_SCOPE_AGENT) < target)
        __builtin_amdgcn_s_sleep(1);
    }
    __syncthreads();
    ++target;
  }
}

// ---------- alpha = sigmoid(c . w + b), one wave per row ----------
__global__ __launch_bounds__(256) void k_alpha(const float* __restrict__ c,
                                               const float* __restrict__ w,
                                               const float* __restrict__ b,
                                               float* __restrict__ alpha) {
  const int wave = threadIdx.x >> 6, lane = threadIdx.x & 63;
  const int t = (blockIdx.x << 2) + wave;
  const float* cr = c + (size_t)t * 512;
  float acc = 0.f;
#pragma unroll
  for (int q = 0; q < 8; ++q) acc = fmaf(cr[lane + (q << 6)], w[lane + (q << 6)], acc);
#pragma unroll
  for (int m = 32; m; m >>= 1) acc += __shfl_xor(acc, m);
  if (lane == 0) alpha[t] = sigmoidf_(acc + b[0]);
}

// ---------- df_out grouped linear + tanh + conv(KT=2) add, one block per row ----------
__global__ __launch_bounds__(256) void k_dfout_conv(const float* __restrict__ c,
                                                    const float* __restrict__ Wd,
                                                    const float* __restrict__ c0,
                                                    const float* __restrict__ wc,
                                                    const float* __restrict__ bc,
                                                    float* __restrict__ out) {
  __shared__ float cs[512];
  __shared__ float A0[64 * 96];
  __shared__ float A1[64 * 96];
  __shared__ float wcs[1280];
  __shared__ float cc[960];
  const int t = blockIdx.x, tid = threadIdx.x;
  ((float2*)cs)[tid] = ((const float2*)(c + (size_t)t * 512))[tid];
  for (int idx = tid; idx < 64 * 96; idx += 256) {
    int ci = idx / 96, f = idx - ci * 96;
    size_t base = (size_t)ci * ((size_t)T_STEPS * 96) + (size_t)t * 96 + f;
    A1[idx] = c0[base];
    A0[idx] = (t == 0) ? 0.f : c0[base - 96];
  }
  for (int idx = tid; idx < 1280; idx += 256) wcs[idx] = wc[idx];
  __syncthreads();
  for (int idx = tid; idx < 960; idx += 256) {
    int f = idx / 10, co = idx - f * 10;
    float acc = bc[co];
    const float* w = wcs + (co << 7);  // (co, ci, kt)
#pragma unroll 16
    for (int ci = 0; ci < 64; ++ci) {
      acc = fmaf(A0[ci * 96 + f], w[ci * 2 + 0], acc);
      acc = fmaf(A1[ci * 96 + f], w[ci * 2 + 1], acc);
    }
    cc[idx] = acc;
  }
  __syncthreads();
  for (int idx = tid; idx < 960; idx += 256) {
    int g = idx / 120, o = idx - g * 120;
    const float* wp = Wd + g * 7680 + o;  // Wd[g][i][o], stride 120 over i
    const float* ep = cs + (g << 6);
    float acc = 0.f;
#pragma unroll 16
    for (int i = 0; i < 64; ++i) acc = fmaf(ep[i], wp[i * 120], acc);
    out[(size_t)t * 960 + idx] = tanhf(acc) + cc[idx];
  }
}

extern "C" void kernel_launch(void* const* d_in, const int* in_sizes, int n_in,
                              void* d_out, int out_size, void* d_ws, size_t ws_size,
                              hipStream_t stream) {
  const float* emb       = (const float*)d_in[0];
  const float* c0        = (const float*)d_in[1];
  const float* lin_in_w  = (const float*)d_in[2];
  const float* w_ih      = (const float*)d_in[3];  // (2,3,512,512)
  const float* w_hh      = (const float*)d_in[4];
  const float* b_ih      = (const float*)d_in[5];  // (2,3,512)
  const float* b_hh      = (const float*)d_in[6];
  const float* skip_w    = (const float*)d_in[7];
  const float* skip_b    = (const float*)d_in[8];
  const float* lin_out_w = (const float*)d_in[9];
  const float* df_skip_w = (const float*)d_in[10];
  const float* df_skip_b = (const float*)d_in[11];
  const float* fc_a_w    = (const float*)d_in[12];
  const float* fc_a_b    = (const float*)d_in[13];
  const float* df_out_w  = (const float*)d_in[14];
  const float* convp_w   = (const float*)d_in[15];
  const float* convp_b   = (const float*)d_in[16];

  const size_t T = T_STEPS;
  float* x    = (float*)d_ws;             // T*512
  float* ih   = x + T * 512;              // T*1536
  float* h1   = ih + T * 1536;            // T*512
  float* b0   = h1 + T * 512;             // 2*512
  float* b1   = b0 + 1024;                // 2*512
  unsigned* flags = (unsigned*)(b1 + 1024);  // 64*32
  float* sbuf = ih;                       // reuse ih region after scan
  float* vbuf = ih + T * 512;
  float* cbuf = ih + 2 * T * 512;
  float* outc = (float*)d_out;
  float* outa = outc + T * 960;

  // x = relu(grouped_linear(emb, lin_in_w))
  k_grouped_relu<<<T_STEPS, 256, 0, stream>>>(emb, lin_in_w, x);
  // ih0 = x @ W_ih0^T + b_ih0
  k_gemm_rr<<<dim3(128, 24), 256, 0, stream>>>(x, w_ih, b_ih, nullptr, ih, 1536);
  // fused pipelined 2-layer scan
  (void)hipMemsetAsync(b0, 0, (1024 + 1024 + NWG2 * 32) * 4, stream);
  k_gru_fused<<<NWG2, 256, 0, stream>>>(ih, w_hh, b_hh,
                                        w_ih + 786432, b_ih + 1536,
                                        w_hh + 786432, b_hh + 1536,
                                        h1, b0, b1, flags);
  // s = h1 + x @ skip_w^T + skip_b
  k_gemm_rr<<<dim3(128, 8), 256, 0, stream>>>(x, skip_w, skip_b, h1, sbuf, 512);
  // v = relu(grouped_linear(s, lin_out_w))
  k_grouped_relu<<<T_STEPS, 256, 0, stream>>>(sbuf, lin_out_w, vbuf);
  // c = v + emb @ df_skip_w^T + df_skip_b
  k_gemm_rr<<<dim3(128, 8), 256, 0, stream>>>(emb, df_skip_w, df_skip_b, vbuf, cbuf, 512);
  // alpha = sigmoid(c @ fc_a_w^T + fc_a_b)
  k_alpha<<<T_STEPS / 4, 256, 0, stream>>>(cbuf, fc_a_w, fc_a_b, outa);
  // out = tanh(grouped_linear(c, df_out_w)) + conv(c0)
  k_dfout_conv<<<T_STEPS, 256, 0, stream>>>(cbuf, df_out_w, c0, convp_w, convp_b, outc);
  (void)in_sizes; (void)n_in; (void)out_size; (void)ws_size;
}